// Round 8
// baseline (172.415 us; speedup 1.0000x reference)
//
#include <hip/hip_runtime.h>
#include <hip/hip_bf16.h>

// ConvT3d(32->16,k3,s2,p1)+BN+4^3 avgpool, bf16 MFMA, 4096-block grid.
// R8 = R5 staging structure EXACTLY (per-plane load->pack->write; R6/R7's
// batched f[5][8] spilled to scratch and cost +28us) + packed cvt +
// raw-acc interior epilogue with analytic bias fold (validated R6/R7).
// Parity decomposition (validated R1-R7): even o: k=1,i=o/2;
//   odd o=2m+1: k=0 -> i=m+1 ; k=2 -> i=m.

typedef __attribute__((ext_vector_type(8))) short bf16x8;
typedef __attribute__((ext_vector_type(4))) float f32x4;

static __device__ __forceinline__ unsigned short f2bf(float f) {
    unsigned int u = __float_as_uint(f);
    u = (u + 0x7fffu + ((u >> 16) & 1u)) >> 16;   // RNE
    return (unsigned short)u;
}
static __device__ __forceinline__ unsigned pack2(float a, float b) {
    union { __hip_bfloat162 h; unsigned u; } cvt;
    cvt.h = __float22bfloat162_rn(make_float2(a, b));   // v_cvt_pk_bf16_f32
    return cvt.u;
}

// ---- w convert: w[ci][co][tap] fp32 -> wT[tap][co][ci] bf16 (tap=kd*9+kh*3+kw)
__global__ __launch_bounds__(256)
void kw(const float* __restrict__ w, unsigned short* __restrict__ wT)
{
    const int idx = blockIdx.x * 256 + threadIdx.x;
    if (idx < 13824) {
        const int ci = idx & 31, co = (idx >> 5) & 15, tap = idx >> 9;
        wT[idx] = f2bf(w[(ci * 16 + co) * 27 + tap]);
    }
}

// ---- fused stage + convT + BN-stats(raw) + pool partials
__global__ __launch_bounds__(256, 3)
void convf2(const float* __restrict__ x,
            const unsigned short* __restrict__ wT,
            const float* __restrict__ bias,
            float* __restrict__ pooled,
            float* __restrict__ psum, float* __restrict__ psq)
{
    const int ht = blockIdx.x, dt = blockIdx.y, n = blockIdx.z;
    const int tid = threadIdx.x;
    const int v = tid >> 6, lane = tid & 63;
    const int t = v & 1, odp = v >> 1;          // ow 16-tile, od pair
    const int c = lane & 15, qd = lane >> 4;    // co / A-row m, K-granule

    // xs[dihi(9)][g(4)][iw(33)][o(8)] bf16 -> 9*1056 shorts = 19008 B
    __shared__ unsigned short xs[9504];
    __shared__ float sred[4][16], qred[4][16], pbuf[2][8][16];

    // ---- stage x (R5 structure): per plane: 8 ci-strided b32 loads,
    // pack -> one ds_write_b128. 5 passes cover 9 planes.
    #pragma unroll
    for (int p = 0; p < 5; ++p) {
        const int dihi = p * 2 + (tid >> 7);
        if (dihi < 9) {
            const int iw = tid & 31, g = (tid >> 5) & 3;
            const int di = dihi / 3, hi = dihi - di * 3;
            const int id = 2*dt + di, ih = 2*ht + hi;
            const bool ok = (id < 32) && (ih < 32);
            const float* px = x + ((((n*32 + g*8)*32 + id)*32 + ih)*32) + iw;
            float f[8];
            #pragma unroll
            for (int j = 0; j < 8; ++j)
                f[j] = ok ? px[j * 32768] : 0.f;
            uint4 u;
            u.x = pack2(f[0], f[1]); u.y = pack2(f[2], f[3]);
            u.z = pack2(f[4], f[5]); u.w = pack2(f[6], f[7]);
            *(uint4*)(xs + dihi*1056 + g*264 + iw*8) = u;
        }
    }
    if (tid < 36) {
        const int dihi = tid >> 2, g = tid & 3;
        *(uint4*)(xs + dihi*1056 + g*264 + 256) = make_uint4(0,0,0,0);
    }

    // ---- B phase 0 (kd=1) prefetched before the barrier (L2-resident wT)
    auto LDBg = [&](int tap) -> bf16x8 {
        return *(const bf16x8*)(wT + tap * 512 + c * 32 + qd * 8);
    };
    bf16x8 Ba[9];
    #pragma unroll
    for (int i = 0; i < 9; ++i) Ba[i] = LDBg(9 + i);

    __syncthreads();

    f32x4 acc[2][4][2];   // [ol][oh][par]
    #pragma unroll
    for (int ol = 0; ol < 2; ++ol)
        #pragma unroll
        for (int oh = 0; oh < 4; ++oh)
            #pragma unroll
            for (int par = 0; par < 2; ++par)
                acc[ol][oh][par] = (f32x4){0.f,0.f,0.f,0.f};

    const int iwb = 16 * t + c;
    auto LDA = [&](int dihi, int sofs) -> bf16x8 {
        return *(const bf16x8*)(xs + dihi*1056 + qd*264 + (iwb + sofs)*8);
    };

    // h-tap tables (validated R2-R7): hi -> (kh, ohl) pairs
    constexpr int HN[3] = {2, 3, 1};
    constexpr int HKH[3][3] = {{1,2,0},{0,1,2},{0,0,0}};
    constexpr int HOH[3][3] = {{0,1,0},{1,2,3},{3,0,0}};

    auto PH = [&](int ol, const bf16x8* B, int di) {
        #pragma unroll
        for (int hi = 0; hi < 3; ++hi) {
            const bf16x8 A0 = LDA(di*3 + hi, 0), A1 = LDA(di*3 + hi, 1);
            #pragma unroll
            for (int j = 0; j < 3; ++j)
                if (j < HN[hi]) {
                    const int kh = HKH[hi][j], oh = HOH[hi][j];
                    acc[ol][oh][0] = __builtin_amdgcn_mfma_f32_16x16x32_bf16(
                        A0, B[kh*3 + 1], acc[ol][oh][0], 0, 0, 0);
                    acc[ol][oh][1] = __builtin_amdgcn_mfma_f32_16x16x32_bf16(
                        A1, B[kh*3 + 0], acc[ol][oh][1], 0, 0, 0);
                    acc[ol][oh][1] = __builtin_amdgcn_mfma_f32_16x16x32_bf16(
                        A0, B[kh*3 + 2], acc[ol][oh][1], 0, 0, 0);
                }
        }
    };

    PH(0, Ba, odp);                                   // kd=1 -> ol0
    #pragma unroll
    for (int i = 0; i < 9; ++i) Ba[i] = LDBg(18 + i);
    PH(1, Ba, odp);                                   // kd=2 -> ol1
    #pragma unroll
    for (int i = 0; i < 9; ++i) Ba[i] = LDBg(i);
    PH(1, Ba, odp + 1);                               // kd=0 -> ol1

    // ---- epilogue: RAW acc stats (bias folded analytically downstream).
    // C/D: co = lane&15, ow-row = 16t+4qd+r, parity par. ow63 = (t1,qd3,r3,par1).
    float s = 0.f, sq = 0.f;
    float P[2] = {0.f, 0.f};
    const bool interior = (dt < 15) && (ht < 15);
    if (interior) {
        #pragma unroll
        for (int ol = 0; ol < 2; ++ol)
            #pragma unroll
            for (int oh = 0; oh < 4; ++oh)
                #pragma unroll
                for (int par = 0; par < 2; ++par)
                    #pragma unroll
                    for (int r = 0; r < 4; ++r) {
                        const float a = acc[ol][oh][par][r];
                        P[r >> 1] += a;
                        sq = fmaf(a, a, sq);
                    }
        s = P[0] + P[1];
        // subtract invalid ow=63 element (rows qd3,r3,par1 of t==1 waves)
        const float mko = (t == 1 && qd == 3) ? 1.f : 0.f;
        #pragma unroll
        for (int ol = 0; ol < 2; ++ol)
            #pragma unroll
            for (int oh = 0; oh < 4; ++oh) {
                const float a = acc[ol][oh][1][3];
                s  = fmaf(-mko, a, s);
                sq = fmaf(-mko * a, a, sq);
            }
    } else {
        #pragma unroll
        for (int ol = 0; ol < 2; ++ol) {
            const int odg = 2*odp + ol;
            const bool odok = !(dt == 15 && odg == 3);
            #pragma unroll
            for (int oh = 0; oh < 4; ++oh) {
                const bool ohok = !(ht == 15 && oh == 3);
                #pragma unroll
                for (int par = 0; par < 2; ++par)
                    #pragma unroll
                    for (int r = 0; r < 4; ++r) {
                        const float a = acc[ol][oh][par][r];
                        const bool owok = !(par == 1 && t == 1 && qd == 3 && r == 3);
                        const float mk = (odok && ohok && owok) ? 1.f : 0.f;
                        s += mk * a; sq += mk * a * a;
                    }
            }
        }
    }
    s  += __shfl_xor(s, 16, 64);  s  += __shfl_xor(s, 32, 64);
    sq += __shfl_xor(sq, 16, 64); sq += __shfl_xor(sq, 32, 64);

    if (lane < 16) { sred[v][lane] = s; qred[v][lane] = sq; }
    if (interior && odp == 0) {
        pbuf[t][2*qd + 0][c] = P[0];
        pbuf[t][2*qd + 1][c] = P[1];
    }
    __syncthreads();
    if (tid < 16) {
        const int blk = (n*16 + dt)*16 + ht;
        psum[tid*4096 + blk] = sred[0][tid]+sred[1][tid]+sred[2][tid]+sred[3][tid];
        psq [tid*4096 + blk] = qred[0][tid]+qred[1][tid]+qred[2][tid]+qred[3][tid];
    }
    if (interior && odp == 1) {
        const float bv = bias[c];
        #pragma unroll
        for (int jj = 0; jj < 2; ++jj) {
            const int jl = 2*qd + jj, jg = 8*t + jl;
            if (jg < 15) {
                const float tot = pbuf[t][jl][c] + P[jj];
                pooled[(n*16 + c)*3375 + dt*225 + ht*15 + jg] =
                    fmaf(tot, 1.f/64.f, bv);
            }
        }
    }
}

__global__ void bnfinal(const float* __restrict__ psum, const float* __restrict__ psq,
                        const float* __restrict__ bias,
                        const float* __restrict__ gamma, const float* __restrict__ beta,
                        float* __restrict__ bn)
{
    const int co = blockIdx.x;
    const int t  = threadIdx.x;
    float S = 0, Q = 0;
    for (int blk = t; blk < 4096; blk += 256) {
        S += psum[co*4096 + blk];
        Q += psq [co*4096 + blk];
    }
    #pragma unroll
    for (int off = 32; off > 0; off >>= 1) {
        S += __shfl_down(S, off, 64);
        Q += __shfl_down(Q, off, 64);
    }
    __shared__ float rs[4], rq[4];
    if ((t & 63) == 0) { rs[t >> 6] = S; rq[t >> 6] = Q; }
    __syncthreads();
    if (t == 0) {
        S = rs[0] + rs[1] + rs[2] + rs[3];
        Q = rq[0] + rq[1] + rq[2] + rq[3];
        const float cnt = 16.f * 63.f * 63.f * 63.f;
        const float bv  = bias[co];
        const float mr  = S / cnt;            // raw mean (pre-bias)
        const float mean = mr + bv;
        const float ey2  = Q / cnt + 2.f * bv * mr + bv * bv;
        const float var  = ey2 - mean * mean;
        const float inv  = rsqrtf(var + 1e-5f);
        const float sc   = inv * gamma[co];
        bn[co]      = sc;
        bn[16 + co] = beta[co] - mean * sc;
    }
}

__global__ void finalize(const float* __restrict__ pooled, const float* __restrict__ bn,
                         float* __restrict__ out)
{
    const int i  = blockIdx.x * 256 + threadIdx.x;   // 864000 = 3375*256
    const int co = (i / 3375) & 15;
    out[i] = pooled[i] * bn[co] + bn[16 + co];
}

extern "C" void kernel_launch(void* const* d_in, const int* in_sizes, int n_in,
                              void* d_out, int out_size, void* d_ws, size_t ws_size,
                              hipStream_t stream)
{
    const float* x     = (const float*)d_in[0];
    const float* w     = (const float*)d_in[1];
    const float* b     = (const float*)d_in[2];
    const float* gamma = (const float*)d_in[3];
    const float* beta  = (const float*)d_in[4];
    float* out = (float*)d_out;

    char* wsb = (char*)d_ws;
    unsigned short* wT = (unsigned short*)wsb;        // 27,648 B
    float* pooled = (float*)(wsb + 27648);            // 3,456,000 B
    float* psum   = (float*)(wsb + 27648 + 3456000);  // 262,144 B
    float* psq    = (float*)(wsb + 27648 + 3456000 + 262144);
    float* bn     = (float*)(wsb + 27648 + 3456000 + 2*262144);

    kw<<<54, 256, 0, stream>>>(w, wT);
    dim3 grid(16, 16, 16);   // (ht, dt, n)
    convf2<<<grid, 256, 0, stream>>>(x, wT, b, pooled, psum, psq);
    bnfinal<<<16, 256, 0, stream>>>(psum, psq, b, gamma, beta, bn);
    finalize<<<3375, 256, 0, stream>>>(pooled, bn, out);
}

// Round 10
// 148.005 us; speedup vs baseline: 1.1649x; 1.1649x over previous
//
#include <hip/hip_runtime.h>

// ConvT3d(32->16,k3,s2,p1)+BN+4^3 avgpool, bf16 MFMA.
// R10: od-pair blocks (8192), waves=(t, ks): ks=0 -> od even (kd=1 phase),
// ks=1 -> od odd (kd=2 + kd=0 phases). MFMA inner body is R5's proven
// 3-mfma pattern verbatim; t/ks readfirstlane'd -> scalar branches only,
// full EXEC at every MFMA (R9's parity-divergent MFMA was the suspect).
// acc=32 f32/wave, 6 staged planes, pooled halves.
// Parity decomposition (validated R1-R8): even o: k=1,i=o/2;
//   odd o=2m+1: k=0 -> i=m+1 ; k=2 -> i=m.

typedef __attribute__((ext_vector_type(8))) short bf16x8;
typedef __attribute__((ext_vector_type(4))) float f32x4;

static __device__ __forceinline__ unsigned short f2bf(float f) {
    unsigned int u = __float_as_uint(f);
    u = (u + 0x7fffu + ((u >> 16) & 1u)) >> 16;   // RNE
    return (unsigned short)u;
}
static __device__ __forceinline__ unsigned pack2(float a, float b) {
    return (unsigned)f2bf(a) | ((unsigned)f2bf(b) << 16);
}

// ---- w convert: w[ci][co][tap] fp32 -> wT[tap][co][ci] bf16 (tap=kd*9+kh*3+kw)
__global__ __launch_bounds__(256)
void kw(const float* __restrict__ w, unsigned short* __restrict__ wT)
{
    const int idx = blockIdx.x * 256 + threadIdx.x;
    if (idx < 13824) {
        const int ci = idx & 31, co = (idx >> 5) & 15, tap = idx >> 9;
        wT[idx] = f2bf(w[(ci * 16 + co) * 27 + tap]);
    }
}

// ---- fused stage + convT + BN-stats + pool partials (od-pair blocks)
__global__ __launch_bounds__(256, 4)
void convf4(const float* __restrict__ x,
            const unsigned short* __restrict__ wT,
            const float* __restrict__ bias,
            float* __restrict__ pooled2,
            float* __restrict__ psum, float* __restrict__ psq)
{
    const int ht = blockIdx.x, dtp = blockIdx.y, n = blockIdx.z;
    const int tid = threadIdx.x;
    const int v = tid >> 6, lane = tid & 63;
    const int t  = __builtin_amdgcn_readfirstlane(v & 1);   // ow 16-tile (SGPR)
    const int ks = __builtin_amdgcn_readfirstlane(v >> 1);  // od parity (SGPR)
    const int c = lane & 15, qd = lane >> 4;    // co / A-row m, K-granule

    // xs[dihi(6)][g(4)][iw(33)][o(8)] bf16 -> 6*1056 shorts = 12672 B
    __shared__ unsigned short xs[6336];
    __shared__ float sred[4][16], qred[4][16], pbuf[2][8][16];

    // ---- stage x (R5 idiom): 768 tasks = (dihi, g, iw); per task 8
    // ci-strided b32 loads -> pack -> one ds_write_b128.
    #pragma unroll
    for (int p = 0; p < 3; ++p) {
        const int task = tid + 256 * p;          // 0..767
        const int dihi = task >> 7;              // 0..5
        const int iw = task & 31, g = (task >> 5) & 3;
        const int di = dihi / 3, hi = dihi - di * 3;   // di 0..1
        const int id = dtp + di, ih = 2*ht + hi;
        const bool ok = (id < 32) && (ih < 32);
        const float* px = x + ((((n*32 + g*8)*32 + id)*32 + ih)*32) + iw;
        float f[8];
        #pragma unroll
        for (int j = 0; j < 8; ++j)
            f[j] = ok ? px[j * 32768] : 0.f;
        uint4 u;
        u.x = pack2(f[0], f[1]); u.y = pack2(f[2], f[3]);
        u.z = pack2(f[4], f[5]); u.w = pack2(f[6], f[7]);
        *(uint4*)(xs + dihi*1056 + g*264 + iw*8) = u;
    }
    if (tid < 24) {       // zero iw=32 halo column
        const int dihi = tid >> 2, g = tid & 3;
        *(uint4*)(xs + dihi*1056 + g*264 + 256) = make_uint4(0,0,0,0);
    }

    // ---- B fragments: 9 taps of one kd at a time (R5 idiom, L2-resident wT)
    auto LDBg = [&](int tap) -> bf16x8 {
        return *(const bf16x8*)(wT + tap * 512 + c * 32 + qd * 8);
    };
    bf16x8 Bf[9];
    const int kdA = ks ? 2 : 1;                 // first phase: kd (SGPR)
    #pragma unroll
    for (int i = 0; i < 9; ++i) Bf[i] = LDBg(kdA*9 + i);

    __syncthreads();

    f32x4 acc[4][2];   // [oh][par] -- 32 f32 per thread
    #pragma unroll
    for (int oh = 0; oh < 4; ++oh)
        #pragma unroll
        for (int par = 0; par < 2; ++par)
            acc[oh][par] = (f32x4){0.f,0.f,0.f,0.f};

    const int iwb = 16 * t + c;
    auto LDA = [&](int dihi, int sofs) -> bf16x8 {
        return *(const bf16x8*)(xs + dihi*1056 + qd*264 + (iwb + sofs)*8);
    };

    // h-tap tables (validated R2-R8): hi -> (kh, ohl) pairs
    constexpr int HN[3] = {2, 3, 1};
    constexpr int HKH[3][3] = {{1,2,0},{0,1,2},{0,0,0}};
    constexpr int HOH[3][3] = {{0,1,0},{1,2,3},{3,0,0}};

    // R5's proven 3-mfma-per-pair body, ol dimension dropped.
    auto PH = [&](int di) {
        #pragma unroll
        for (int hi = 0; hi < 3; ++hi) {
            const bf16x8 A0 = LDA(di*3 + hi, 0), A1 = LDA(di*3 + hi, 1);
            #pragma unroll
            for (int j = 0; j < 3; ++j)
                if (j < HN[hi]) {
                    const int kh = HKH[hi][j], oh = HOH[hi][j];
                    acc[oh][0] = __builtin_amdgcn_mfma_f32_16x16x32_bf16(
                        A0, Bf[kh*3 + 1], acc[oh][0], 0, 0, 0);
                    acc[oh][1] = __builtin_amdgcn_mfma_f32_16x16x32_bf16(
                        A1, Bf[kh*3 + 0], acc[oh][1], 0, 0, 0);
                    acc[oh][1] = __builtin_amdgcn_mfma_f32_16x16x32_bf16(
                        A0, Bf[kh*3 + 2], acc[oh][1], 0, 0, 0);
                }
        }
    };

    PH(0);                 // ks=0: kd=1,i=dtp (od even) ; ks=1: kd=2,i=dtp (od odd)
    if (ks) {              // scalar branch (ks is SGPR); full EXEC inside
        #pragma unroll
        for (int i = 0; i < 9; ++i) Bf[i] = LDBg(i);   // kd=0
        PH(1);             // kd=0, i=dtp+1 (od odd)
    }

    // ---- epilogue (R5-style): bias in vals, masked stats, pool partials.
    // Wave covers od = 2dtp+ks; element (oh,par,r): ow = 32t+8qd+2r+par.
    const bool odok = (2*dtp + ks) < 63;        // wave-uniform
    const float bv = bias[c];
    float s = 0.f, sq = 0.f;
    float P[2] = {0.f, 0.f};
    #pragma unroll
    for (int oh = 0; oh < 4; ++oh) {
        const bool ohok = !(ht == 15 && oh == 3);
        #pragma unroll
        for (int par = 0; par < 2; ++par)
            #pragma unroll
            for (int r = 0; r < 4; ++r) {
                const float val = acc[oh][par][r] + bv;
                const bool owok = !(par == 1 && t == 1 && qd == 3 && r == 3);
                const float mk = (odok && ohok && owok) ? 1.f : 0.f;
                s += mk * val; sq += mk * val * val;
                P[r >> 1] += val;
            }
    }
    s  += __shfl_xor(s, 16, 64);  s  += __shfl_xor(s, 32, 64);
    sq += __shfl_xor(sq, 16, 64); sq += __shfl_xor(sq, 32, 64);

    const int dq = dtp >> 1, half = dtp & 1;
    const bool pok = (dq < 15) && (ht < 15);
    if (lane < 16) { sred[v][lane] = s; qred[v][lane] = sq; }
    if (ks == 0 && pok) {
        pbuf[t][2*qd + 0][c] = P[0];
        pbuf[t][2*qd + 1][c] = P[1];
    }
    __syncthreads();
    if (tid < 16) {
        const int blk = (n*32 + dtp)*16 + ht;
        psum[tid*8192 + blk] = sred[0][tid]+sred[1][tid]+sred[2][tid]+sred[3][tid];
        psq [tid*8192 + blk] = qred[0][tid]+qred[1][tid]+qred[2][tid]+qred[3][tid];
    }
    if (ks == 1 && pok) {
        #pragma unroll
        for (int jj = 0; jj < 2; ++jj) {
            const int jl = 2*qd + jj, jg = 8*t + jl;
            if (jg < 15)
                pooled2[half*864000 + (n*16 + c)*3375 + dq*225 + ht*15 + jg] =
                    pbuf[t][jl][c] + P[jj];
        }
    }
}

__global__ void bnfinal(const float* __restrict__ psum, const float* __restrict__ psq,
                        const float* __restrict__ gamma, const float* __restrict__ beta,
                        float* __restrict__ bn)
{
    const int co = blockIdx.x;
    const int t  = threadIdx.x;
    float S = 0, Q = 0;
    for (int blk = t; blk < 8192; blk += 256) {
        S += psum[co*8192 + blk];
        Q += psq [co*8192 + blk];
    }
    #pragma unroll
    for (int off = 32; off > 0; off >>= 1) {
        S += __shfl_down(S, off, 64);
        Q += __shfl_down(Q, off, 64);
    }
    __shared__ float rs[4], rq[4];
    if ((t & 63) == 0) { rs[t >> 6] = S; rq[t >> 6] = Q; }
    __syncthreads();
    if (t == 0) {
        S = rs[0] + rs[1] + rs[2] + rs[3];
        Q = rq[0] + rq[1] + rq[2] + rq[3];
        const float cnt = 16.f * 63.f * 63.f * 63.f;
        const float mean = S / cnt;
        const float var  = Q / cnt - mean * mean;
        const float inv  = rsqrtf(var + 1e-5f);
        const float sc   = inv * gamma[co];
        bn[co]      = sc;
        bn[16 + co] = beta[co] - mean * sc;
    }
}

__global__ void finalize(const float* __restrict__ pooled2, const float* __restrict__ bn,
                         float* __restrict__ out)
{
    const int i  = blockIdx.x * 256 + threadIdx.x;   // 864000 = 3375*256
    const int co = (i / 3375) & 15;
    const float tot = pooled2[i] + pooled2[864000 + i];
    out[i] = tot * (1.f/64.f) * bn[co] + bn[16 + co];
}

extern "C" void kernel_launch(void* const* d_in, const int* in_sizes, int n_in,
                              void* d_out, int out_size, void* d_ws, size_t ws_size,
                              hipStream_t stream)
{
    const float* x     = (const float*)d_in[0];
    const float* w     = (const float*)d_in[1];
    const float* b     = (const float*)d_in[2];
    const float* gamma = (const float*)d_in[3];
    const float* beta  = (const float*)d_in[4];
    float* out = (float*)d_out;

    char* wsb = (char*)d_ws;
    unsigned short* wT = (unsigned short*)wsb;           // 27,648 B
    float* pooled2 = (float*)(wsb + 27648);              // 2*864000*4 = 6,912,000 B
    float* psum    = (float*)(wsb + 27648 + 6912000);    // 16*8192*4 = 524,288 B
    float* psq     = (float*)(wsb + 27648 + 6912000 + 524288);
    float* bn      = (float*)(wsb + 27648 + 6912000 + 2*524288);

    kw<<<54, 256, 0, stream>>>(w, wT);
    dim3 grid(16, 32, 16);   // (ht, dtp, n)
    convf4<<<grid, 256, 0, stream>>>(x, wT, b, pooled2, psum, psq);
    bnfinal<<<16, 256, 0, stream>>>(psum, psq, gamma, beta, bn);
    finalize<<<3375, 256, 0, stream>>>(pooled2, bn, out);
}